// Round 6
// baseline (129.401 us; speedup 1.0000x reference)
//
#include <hip/hip_runtime.h>
#include <math.h>

// DirectionalContrastiveLoss — N=8, C=192, H=W=112, T=0.1
//
// R11: barrier-free main loop via wave-private LDS tiles.
//  Evidence: R7/R8/R10 all land at ~22-25us kernel despite very different
//  occupancy/halo/XCD layouts -> the 12 per-chunk __syncthreads are the
//  common bottleneck (pipes: HBM ~12us, LDS ~11us, VALU ~13us; observed 25
//  = bad overlap). CDNA DS ops from one wave complete in order, so a
//  wave-private tile needs NO barrier: ds_write(t+1) issued after
//  ds_read(t) cannot clobber (WAR ordered), reads after writes see new
//  data (RAW ordered). Single-buffered, zero main-loop barriers.
//  - block = 4 waves; wave q owns channels [48q,48q+48) of an 8x14 px tile.
//  - wave tile: halo 10x16 = 160 slots, rows padded to 17 v4f (2-way banks).
//  - 896 blocks (14x8 tiles x 8 img, XCD swizzle n=bid&7); 40.1 KB LDS ->
//    3 blocks/CU = 12 independent waves/CU backfill every stall.
//  - vertical pairs: 4 pair-rows x 14 = 56 lanes cover all 8 rows exactly.
//  - one __syncthreads total (quarter-combine before epilogue).

namespace {
constexpr int N_ = 8, C_ = 192, H_ = 112, W_ = 112;
constexpr int HW = H_ * W_;
constexpr int TH = 8, WS = 14;         // pixel tile per block
constexpr int TCOLS = 16;              // halo cols (rows = 10)
constexpr int ROWP = 17;               // padded row stride (v4f units)
constexpr int NSLOT = 160;             // 10 x 16 halo slots
constexpr int NT = 256;                // 4 waves
constexpr int NPAIR = 4 * WS;          // 56 pair lanes per wave
constexpr int QCH = C_ / 4;            // 48 channels per wave
constexpr int KCH = 8;                 // channels per chunk
constexpr int GRP = 2;                 // 2 v4f per chunk-slot
constexpr int NCH = QCH / KCH;         // 6 chunks
constexpr int NBLK = (H_ / TH) * (W_ / WS) * N_;   // 14*8*8 = 896
constexpr float INV_T = 10.0f;
constexpr double TOTAL = (double)N_ * N_ * H_ * W_;  // 802816
}

typedef float v2f __attribute__((ext_vector_type(2)));
typedef float v4f __attribute__((ext_vector_type(4)));

__device__ __forceinline__ void pk(v2f& a, v2f x, v2f y) {
    asm("v_pk_fma_f32 %0, %1, %2, %0" : "+v"(a) : "v"(x), "v"(y));
}
__device__ __forceinline__ void pk4(v2f& a, v4f x, v4f y) {
    pk(a, x.lo, y.lo); pk(a, x.hi, y.hi);
}

__device__ __forceinline__ float sel3(int d, float a, float b, float c) {
    float r = (d < 0) ? a : b;
    return (d > 0) ? c : r;
}

extern "C" __global__ void __launch_bounds__(NT, 3)
dcl_main(const float* __restrict__ feat,
         const int* __restrict__ labels,
         const int* __restrict__ dirs,
         double* __restrict__ partial, int use_partial)
{
    __shared__ v4f   tilesA[4][GRP][10 * ROWP];   // 21.8 KB, wave-private
    __shared__ float ssq[4][NSLOT];               // 2.56 KB
    __shared__ float ssbuf[NSLOT];                // 0.64 KB
    __shared__ float part[4][NPAIR][18];          // 16.1 KB
    __shared__ float red[4];

    const int bid = blockIdx.x;
    const int n   = bid & 7;            // XCD swizzle: image n
    const int tt  = bid >> 3;           // 0..111
    const int tyb = tt >> 3;            // 0..13
    const int txb = tt & 7;             // 0..7
    const int gy0 = tyb * TH;
    const int gx0 = txb * WS;

    const int tid  = threadIdx.x;
    const int q    = tid >> 6;          // channel quarter / wave id
    const int lane = tid & 63;

    // ---- staging slots: lane owns slot lane, lane+64, (+128 if lane<32)
    const bool l32 = (lane < 32);
    int li0, go0, li1, go1, li2 = 0, go2 = 0;
    {
        int s = lane, r = s >> 4, c = s & 15;
        li0 = r * ROWP + c;
        go0 = min(max(gy0 + r - 1, 0), H_ - 1) * W_ + min(max(gx0 + c - 1, 0), W_ - 1);
        s = lane + 64; r = s >> 4; c = s & 15;
        li1 = r * ROWP + c;
        go1 = min(max(gy0 + r - 1, 0), H_ - 1) * W_ + min(max(gx0 + c - 1, 0), W_ - 1);
        if (l32) {
            s = lane + 128; r = s >> 4; c = s & 15;
            li2 = r * ROWP + c;
            go2 = min(max(gy0 + r - 1, 0), H_ - 1) * W_ + min(max(gx0 + c - 1, 0), W_ - 1);
        }
    }

    // ---- pair mapping: lane < 56 owns image rows (2pr, 2pr+1), col tx
    const bool is_pr = (lane < NPAIR);
    const int pr = lane / WS;            // 0..3
    const int tx = lane - pr * WS;       // 0..13
    const int top = (2 * pr) * ROWP + tx;

    const float* __restrict__ plane =
        feat + ((size_t)n * C_ + (size_t)q * QCH) * HW;

    float ss0 = 0.f, ss1 = 0.f, ss2 = 0.f;
    float pva[KCH], pvb[KCH], pvc[KCH];

    auto ld = [&](int go, int t, float* pv) {
        const float* p = plane + (size_t)t * KCH * HW + go;
        #pragma unroll
        for (int k = 0; k < KCH; ++k) pv[k] = p[(size_t)k * HW];
    };
    auto wr = [&](int li, const float* pv, float& ss) {
        ss += pv[0]*pv[0] + pv[1]*pv[1] + pv[2]*pv[2] + pv[3]*pv[3]
            + pv[4]*pv[4] + pv[5]*pv[5] + pv[6]*pv[6] + pv[7]*pv[7];
        v4f a = {pv[0], pv[1], pv[2], pv[3]};
        v4f b = {pv[4], pv[5], pv[6], pv[7]};
        tilesA[q][0][li] = a;
        tilesA[q][1][li] = b;
    };

    // ---- prologue: stage chunk 0 (no barrier: same-wave DS is in-order)
    ld(go0, 0, pva); ld(go1, 0, pvb); if (l32) ld(go2, 0, pvc);
    wr(li0, pva, ss0); wr(li1, pvb, ss1); if (l32) wr(li2, pvc, ss2);

    // q0: px0 dirs {(-1,-1),(-1,0),(-1,1),(0,-1),(0,1),(1,-1),(1,1)}; s01=(1,0)
    // q1: px1 dirs {(-1,-1),(-1,1),(0,-1),(0,1),(1,-1),(1,0),(1,1)}; (-1,0)=s01
    v2f q0[7], q1[7], s01;
    {
        const v2f z = {0.f, 0.f};
        #pragma unroll
        for (int d = 0; d < 7; ++d) { q0[d] = z; q1[d] = z; }
        s01 = z;
    }

    // ---- chunk loop: ZERO barriers
    for (int t = 0; t < NCH; ++t) {
        const bool more = (t + 1 < NCH);
        if (more) {
            ld(go0, t + 1, pva); ld(go1, t + 1, pvb); if (l32) ld(go2, t + 1, pvc);
        }
        if (is_pr) {
            #pragma unroll
            for (int g = 0; g < GRP; ++g) {
                const v4f* __restrict__ cp = &tilesA[q][g][0];
                v4f A0 = cp[top +  0], B0 = cp[top +  1], C0 = cp[top +  2];
                v4f A1 = cp[top + 17], B1 = cp[top + 18], C1 = cp[top + 19];
                v4f A2 = cp[top + 34], B2 = cp[top + 35], C2 = cp[top + 36];
                // px0 (center B1)
                pk4(q0[0], B1, A0); pk4(q0[1], B1, B0); pk4(q0[2], B1, C0);
                pk4(q0[3], B1, A1); pk4(q0[4], B1, C1);
                pk4(q0[5], B1, A2); pk4(s01,   B1, B2); pk4(q0[6], B1, C2);
                v4f A3 = cp[top + 51], B3 = cp[top + 52], C3 = cp[top + 53];
                // px1 (center B2); (-1,0) shared via s01
                pk4(q1[0], B2, A1); pk4(q1[1], B2, C1);
                pk4(q1[2], B2, A2); pk4(q1[3], B2, C2);
                pk4(q1[4], B2, A3); pk4(q1[5], B2, B3); pk4(q1[6], B2, C3);
            }
        }
        if (more) {   // overwrite tile: WAR-safe (same-wave DS in-order)
            wr(li0, pva, ss0); wr(li1, pvb, ss1); if (l32) wr(li2, pvc, ss2);
        }
    }

    // ---- publish quarter partials (the ONLY barrier)
    ssq[q][lane] = ss0;
    ssq[q][lane + 64] = ss1;
    if (l32) ssq[q][lane + 128] = ss2;
    if (is_pr) {
        float* d = part[q][lane];
        d[0] = q0[0].x + q0[0].y;  d[1] = q0[1].x + q0[1].y;
        d[2] = q0[2].x + q0[2].y;  d[3] = q0[3].x + q0[3].y;
        d[4] = q0[4].x + q0[4].y;  d[5] = q0[5].x + q0[5].y;
        d[6] = s01.x + s01.y;      d[7] = q0[6].x + q0[6].y;
        d[8]  = q1[0].x + q1[0].y; d[9]  = s01.x + s01.y;
        d[10] = q1[1].x + q1[1].y; d[11] = q1[2].x + q1[2].y;
        d[12] = q1[3].x + q1[3].y; d[13] = q1[4].x + q1[4].y;
        d[14] = q1[5].x + q1[5].y; d[15] = q1[6].x + q1[6].y;
    }
    __syncthreads();
    if (tid < NSLOT)
        ssbuf[tid] = 1.0f / fmaxf(
            sqrtf(ssq[0][tid] + ssq[1][tid] + ssq[2][tid] + ssq[3][tid]), 1e-12f);
    __syncthreads();

    // ---- epilogue: threads 0..111 own one pixel each
    float lp = 0.0f;
    if (tid < TH * WS) {
        const int er = tid / WS, ec = tid - (tid / WS) * WS;  // row 0..7, col 0..13
        const int lane_ = (er >> 1) * WS + ec;
        const int off = (er & 1) * 8;
        float f[8];
        #pragma unroll
        for (int k = 0; k < 8; ++k)
            f[k] = part[0][lane_][off + k] + part[1][lane_][off + k]
                 + part[2][lane_][off + k] + part[3][lane_][off + k];

        const int ciu = (er + 1) * TCOLS + (ec + 1);
        const float ssqc = ssq[0][ciu] + ssq[1][ciu] + ssq[2][ciu] + ssq[3][ciu];
        const float invc = ssbuf[ciu] * INV_T;
        const float l00 = f[0] * invc * ssbuf[ciu - TCOLS - 1];
        const float l01 = f[1] * invc * ssbuf[ciu - TCOLS];
        const float l02 = f[2] * invc * ssbuf[ciu - TCOLS + 1];
        const float l10 = f[3] * invc * ssbuf[ciu - 1];
        const float l11 = ssqc * invc * ssbuf[ciu];
        const float l12 = f[4] * invc * ssbuf[ciu + 1];
        const float l20 = f[5] * invc * ssbuf[ciu + TCOLS - 1];
        const float l21 = f[6] * invc * ssbuf[ciu + TCOLS];
        const float l22 = f[7] * invc * ssbuf[ciu + TCOLS + 1];

        const int gi = gy0 + er, gj = gx0 + ec;
        const int pix = gi * W_ + gj;
        float denom = 0.f, sumlog = 0.f;
        #pragma unroll
        for (int m = 0; m < N_; ++m) {
            int d0 = dirs[((m * 2 + 0) * H_ + gi) * W_ + gj];
            int d1 = dirs[((m * 2 + 1) * H_ + gi) * W_ + gj];
            float e0 = sel3(d1, l00, l01, l02);
            float e1 = sel3(d1, l10, l11, l12);
            float e2 = sel3(d1, l20, l21, l22);
            float lm = sel3(d0, e0, e1, e2);
            int labm = labels[m * HW + pix];
            int labn = labels[n * HW + (gi + d0) * W_ + (gj + d1)];
            bool msk = (labm == labn);
            float e = msk ? __expf(lm) : 0.f;
            denom += e;
            sumlog += msk ? lm : -INFINITY;
        }
        lp = 8.0f * __logf(denom + 1e-6f) - sumlog;
    }

    // ---- block reduction (4 waves)
    #pragma unroll
    for (int off = 32; off > 0; off >>= 1) lp += __shfl_down(lp, off, 64);
    const int wv = tid >> 6, ln = tid & 63;
    if (ln == 0) red[wv] = lp;
    __syncthreads();
    if (tid == 0) {
        float tsum = red[0] + red[1] + red[2] + red[3];
        if (use_partial) partial[bid] = (double)tsum;
        else atomicAdd(partial, (double)tsum);
    }
}

extern "C" __global__ void __launch_bounds__(256)
dcl_final(const double* __restrict__ partial, float* __restrict__ out, int nblk)
{
    const int tid = threadIdx.x;
    double s = 0.0;
    for (int i = tid; i < nblk; i += 256) s += partial[i];
    #pragma unroll
    for (int off = 32; off > 0; off >>= 1) s += __shfl_down(s, off, 64);
    __shared__ double red[4];
    const int lane = tid & 63, wv = tid >> 6;
    if (lane == 0) red[wv] = s;
    __syncthreads();
    if (tid == 0) out[0] = (float)((red[0] + red[1] + red[2] + red[3]) / TOTAL);
}

extern "C" void kernel_launch(void* const* d_in, const int* in_sizes, int n_in,
                              void* d_out, int out_size, void* d_ws, size_t ws_size,
                              hipStream_t stream) {
    const float* feat   = (const float*)d_in[0];
    const int*   labels = (const int*)d_in[1];
    const int*   dirs   = (const int*)d_in[2];
    double* acc = (double*)d_ws;
    float*  out = (float*)d_out;

    const int use_partial = (ws_size >= (size_t)NBLK * sizeof(double)) ? 1 : 0;
    if (!use_partial) hipMemsetAsync(acc, 0, sizeof(double), stream);
    dcl_main<<<dim3(NBLK), NT, 0, stream>>>(feat, labels, dirs, acc, use_partial);
    dcl_final<<<1, 256, 0, stream>>>(acc, out, use_partial ? NBLK : 1);
}